// Round 8
// baseline (585.136 us; speedup 1.0000x reference)
//
#include <hip/hip_runtime.h>
#include <hip/hip_bf16.h>

// PAM (position attention): B=8, C=512, mid=64, N=64*64=4096.
// Round 8:
//  - k_attn: block tile 64i x 256c (grid 1024) + __launch_bounds__(512,4) so
//    TWO blocks co-reside per CU (round-7 was 1 block => phases summed).
//    Per-wave regs ~115 (acc 32 + Q 8 + K ping-pong 32 + V single-buf 16).
//    Same pipeline: region = {V load, QK(t+1), K(t+2) prefetch, exp2+cvt_pk
//    +store P(t+1)->buf^1, PV(t) from buf} -> lgkm-only barrier.
//  - k_transpose vectorized (f32x4 loads, ushort4 stores).
//  - k_proj V-path n-tile 256 (halved xT/wv re-reads).

#define BB 8
#define CC 512
#define MM 64
#define NN 4096
#define LOG2E 1.4426950408889634f

typedef __attribute__((ext_vector_type(8))) short bf16x8;
typedef __attribute__((ext_vector_type(8))) _Float16 f16x8;
typedef __attribute__((ext_vector_type(4))) float f32x4;

__device__ unsigned g_kmax[BB];  // per-batch max ||k||^2 (uint-ordered f32)

__device__ __forceinline__ unsigned short f2bf(float f) {
  union { float f; unsigned u; } v; v.f = f;
  unsigned r = v.u + 0x7fffu + ((v.u >> 16) & 1u);  // RNE
  return (unsigned short)(r >> 16);
}
__device__ __forceinline__ float bf2f(unsigned short h) {
  union { unsigned u; float f; } v; v.u = ((unsigned)h) << 16;
  return v.f;
}
__device__ __forceinline__ unsigned short f2h(float f) {
  union { _Float16 h; unsigned short u; } v; v.h = (_Float16)f;
  return v.u;
}

// ------------- kernel 0: weight pre-conversion + g_kmax init -------------
__global__ __launch_bounds__(256) void k_wconv(
    const float* __restrict__ wq, const float* __restrict__ wk,
    const float* __restrict__ wv,
    unsigned short* __restrict__ wqhi, unsigned short* __restrict__ wqlo,
    unsigned short* __restrict__ wkhi, unsigned short* __restrict__ wklo,
    unsigned short* __restrict__ wvbf) {
  const int tid = blockIdx.x * 256 + threadIdx.x;
  if (tid < BB) g_kmax[tid] = 0u;
  if (tid < MM * CC) {
    float v = wq[tid];
    unsigned short h = f2bf(v);
    wqhi[tid] = h; wqlo[tid] = f2bf(v - bf2f(h));
    v = wk[tid]; h = f2bf(v);
    wkhi[tid] = h; wklo[tid] = f2bf(v - bf2f(h));
  }
  for (int i = tid; i < CC * CC; i += 65536) wvbf[i] = f2bf(wv[i]);
}

// ---------------- kernel 1: x [B][C][N] f32 -> xT [B][N][C] bf16 ----------------
__global__ __launch_bounds__(256) void k_transpose(const float* __restrict__ x,
                                                   unsigned short* __restrict__ xT) {
  __shared__ float tile[64][65];
  const int b = blockIdx.z, c0 = blockIdx.y * 64, n0 = blockIdx.x * 64;
  const int t = threadIdx.x;
  {
    const int nq = (t & 15) * 4, cl0 = t >> 4;
    const float* xp = x + ((size_t)b * CC + c0) * NN + n0;
#pragma unroll
    for (int r = 0; r < 4; r++) {
      const int row = cl0 + r * 16;
      const f32x4 v = *reinterpret_cast<const f32x4*>(xp + (size_t)row * NN + nq);
      tile[row][nq] = v[0]; tile[row][nq + 1] = v[1];
      tile[row][nq + 2] = v[2]; tile[row][nq + 3] = v[3];
    }
  }
  __syncthreads();
  {
    const int cq = (t & 15) * 4, nl0 = t >> 4;
    unsigned short* xtp = xT + ((size_t)b * NN + n0) * CC + c0;
#pragma unroll
    for (int r = 0; r < 4; r++) {
      const int n = nl0 + r * 16;
      const ushort4 o = make_ushort4(f2bf(tile[cq][n]), f2bf(tile[cq + 1][n]),
                                     f2bf(tile[cq + 2][n]), f2bf(tile[cq + 3][n]));
      *reinterpret_cast<ushort4*>(xtp + (size_t)n * CC + cq) = o;
    }
  }
}

// ------------- kernel 2 (fused): Q/K projection (blocks 0..511) +
//                                 V projection (blocks 512..1535, n-tile 256) -------------
__global__ __launch_bounds__(256, 2) void k_proj(
    const unsigned short* __restrict__ xT,
    const unsigned short* __restrict__ wqhi, const unsigned short* __restrict__ wqlo,
    const unsigned short* __restrict__ wkhi, const unsigned short* __restrict__ wklo,
    const float* __restrict__ bq, const float* __restrict__ bk,
    const unsigned short* __restrict__ wvbf, const float* __restrict__ bv,
    unsigned short* __restrict__ qf, unsigned short* __restrict__ kf,
    unsigned short* __restrict__ vbf) {
  __shared__ float ksl[4][4][16];
  const int t = threadIdx.x, w = t >> 6, l = t & 63, lr = l & 15, g = l >> 4;

  if (blockIdx.x < 512) {
    // ---- Q/K projection: 2-term hi/lo bf16 MFMA; q pre-scaled by log2e
    const int b = blockIdx.x & 7;
    const int n0 = (blockIdx.x >> 3) * 64;
    const unsigned short* qhp = wqhi + (size_t)(w * 16 + lr) * CC + g * 8;
    const unsigned short* qlp = wqlo + (size_t)(w * 16 + lr) * CC + g * 8;
    const unsigned short* khp = wkhi + (size_t)(w * 16 + lr) * CC + g * 8;
    const unsigned short* klp = wklo + (size_t)(w * 16 + lr) * CC + g * 8;
    const unsigned short* xp = xT + ((size_t)b * NN + n0 + lr) * CC + g * 8;
    f32x4 qacc[4], kacc[4];
#pragma unroll
    for (int nf = 0; nf < 4; nf++) {
      qacc[nf] = f32x4{0.f, 0.f, 0.f, 0.f};
      kacc[nf] = f32x4{0.f, 0.f, 0.f, 0.f};
    }
    for (int cc = 0; cc < CC; cc += 32) {
      const bf16x8 qh8 = *reinterpret_cast<const bf16x8*>(qhp + cc);
      const bf16x8 ql8 = *reinterpret_cast<const bf16x8*>(qlp + cc);
      const bf16x8 kh8 = *reinterpret_cast<const bf16x8*>(khp + cc);
      const bf16x8 kl8 = *reinterpret_cast<const bf16x8*>(klp + cc);
      bf16x8 xb[4];
#pragma unroll
      for (int nf = 0; nf < 4; nf++)
        xb[nf] = *reinterpret_cast<const bf16x8*>(xp + (size_t)nf * 16 * CC + cc);
#pragma unroll
      for (int nf = 0; nf < 4; nf++) {
        qacc[nf] = __builtin_amdgcn_mfma_f32_16x16x32_bf16(qh8, xb[nf], qacc[nf], 0, 0, 0);
        qacc[nf] = __builtin_amdgcn_mfma_f32_16x16x32_bf16(ql8, xb[nf], qacc[nf], 0, 0, 0);
        kacc[nf] = __builtin_amdgcn_mfma_f32_16x16x32_bf16(kh8, xb[nf], kacc[nf], 0, 0, 0);
        kacc[nf] = __builtin_amdgcn_mfma_f32_16x16x32_bf16(kl8, xb[nf], kacc[nf], 0, 0, 0);
      }
    }
    float bqv[4], bkv[4];
#pragma unroll
    for (int r = 0; r < 4; r++) {
      bqv[r] = bq[w * 16 + g * 4 + r];
      bkv[r] = bk[w * 16 + g * 4 + r];
    }
    float kssp[4];
#pragma unroll
    for (int nf = 0; nf < 4; nf++) {
      float ks2 = 0.f;
      unsigned short qh[4], kh[4];
#pragma unroll
      for (int r = 0; r < 4; r++) {
        const float qv = (qacc[nf][r] + bqv[r]) * LOG2E;
        const float kv = kacc[nf][r] + bkv[r];
        qh[r] = f2h(qv); kh[r] = f2h(kv);
        ks2 += kv * kv;
      }
      kssp[nf] = ks2;
      const int n = n0 + nf * 16 + lr;
      const size_t base = ((size_t)b * NN + n) * MM + w * 16 + g * 4;
      *reinterpret_cast<ushort4*>(qf + base) = make_ushort4(qh[0], qh[1], qh[2], qh[3]);
      *reinterpret_cast<ushort4*>(kf + base) = make_ushort4(kh[0], kh[1], kh[2], kh[3]);
    }
#pragma unroll
    for (int nf = 0; nf < 4; nf++) {
      kssp[nf] += __shfl_xor(kssp[nf], 16);
      kssp[nf] += __shfl_xor(kssp[nf], 32);
    }
    if (l < 16) {
#pragma unroll
      for (int nf = 0; nf < 4; nf++) ksl[w][nf][lr] = kssp[nf];
    }
    __syncthreads();
    if (t < 64) {
      const int nf2 = t >> 4, lr2 = t & 15;
      float kn2 = ksl[0][nf2][lr2] + ksl[1][nf2][lr2] + ksl[2][nf2][lr2] + ksl[3][nf2][lr2];
#pragma unroll
      for (int d = 1; d < 64; d <<= 1) kn2 = fmaxf(kn2, __shfl_xor(kn2, d));
      if (t == 0) atomicMax(&g_kmax[b], __float_as_uint(kn2));
    }
  } else {
    // ---- V projection (bf16 MFMA, pre-converted wv), n-tile 256
    const int blk = blockIdx.x - 512;                 // 0..1023
    const int b = blk >> 7, c0 = ((blk >> 4) & 7) * 64, n0 = (blk & 15) * 256;
    const int nbase = n0 + w * 64;
    f32x4 acc[4][4];
#pragma unroll
    for (int cf = 0; cf < 4; cf++)
#pragma unroll
      for (int nf = 0; nf < 4; nf++) acc[cf][nf] = f32x4{0.f, 0.f, 0.f, 0.f};
    for (int ks = 0; ks < 16; ks++) {
      const int kk = ks * 32 + g * 8;
      bf16x8 bfr[4];
#pragma unroll
      for (int nf = 0; nf < 4; nf++) {
        const int n = nbase + nf * 16 + lr;
        bfr[nf] = *reinterpret_cast<const bf16x8*>(xT + ((size_t)b * NN + n) * CC + kk);
      }
#pragma unroll
      for (int cf = 0; cf < 4; cf++) {
        const bf16x8 af = *reinterpret_cast<const bf16x8*>(
            wvbf + (size_t)(c0 + cf * 16 + lr) * CC + kk);
#pragma unroll
        for (int nf = 0; nf < 4; nf++)
          acc[cf][nf] = __builtin_amdgcn_mfma_f32_16x16x32_bf16(af, bfr[nf], acc[cf][nf], 0, 0, 0);
      }
    }
#pragma unroll
    for (int cf = 0; cf < 4; cf++) {
#pragma unroll
      for (int r = 0; r < 4; r++) {
        const int c = c0 + cf * 16 + g * 4 + r;
        const float bvv = bv[c];
#pragma unroll
        for (int nf = 0; nf < 4; nf++) {
          const int n = nbase + nf * 16 + lr;
          vbf[((size_t)b * CC + c) * NN + n] = f2bf(acc[cf][nf][r] + bvv);
        }
      }
    }
  }
}

// ---------------- kernel 3: attention + residual (bound-softmax) ----------------
// 8 waves (512 thr); block = 64 i x 256 c; grid 1024 (8b x 2ch x 64 i-tiles);
// __launch_bounds__(512,4) -> 2 blocks/CU co-resident (TLP overlap).
// QK fp16 swapped (A=K,B=Q): wave w -> i-frag (w&3), j-frag pair (w>>2).
// Region t: {V(t) load, QK(t+1), K(t+2) prefetch, exp2+cvt_pk+store P->buf^1,
//            PV(t) from buf} -> lgkm-only barrier (globals stay in flight).
__global__ __launch_bounds__(512, 4) void k_attn(
    const unsigned short* __restrict__ qf, const unsigned short* __restrict__ kf,
    const unsigned short* __restrict__ vbf, const float* __restrict__ x,
    const float* __restrict__ gamma, float* __restrict__ out) {
  __shared__ unsigned short P_lds[2][64][64];  // 8 KB per buffer, XOR-swizzled
  __shared__ float l_red[8][16];
  const int b = blockIdx.x & 7;      // batch-pinned XCD swizzle
  const int idx = blockIdx.x >> 3;   // 0..127
  const int i0 = (idx >> 1) * 64;
  const int ch = idx & 1;
  const int t = threadIdx.x, w = t >> 6, l = t & 63, lr = l & 15, g = l >> 4;
  const int if_ = w & 3;             // i-frag (this wave's QK output columns)
  const int jp = w >> 2;             // j-frag pair (0 or 1)
  const int wc = ch * 256 + w * 32;  // PV channel strip (32 c per wave)

  // ---- Q fragment (fp16, pre-scaled by log2e): i = i0 + if_*16 + lr
  f16x8 qF[2];
  {
    const int i = i0 + if_ * 16 + lr;
#pragma unroll
    for (int ks = 0; ks < 2; ks++)
      qF[ks] = *reinterpret_cast<const f16x8*>(qf + ((size_t)b * NN + i) * MM + ks * 32 + g * 8);
  }
  // ---- mhat (log2 units): ||q~|| * max||k|| * (1+eps) - 44*log2e
  float mhat;
  {
    float ssq = 0.f;
#pragma unroll
    for (int ks = 0; ks < 2; ks++)
#pragma unroll
      for (int e = 0; e < 8; e++) {
        const float qv = (float)qF[ks][e];
        ssq += qv * qv;
      }
    ssq += __shfl_xor(ssq, 16);
    ssq += __shfl_xor(ssq, 32);
    mhat = sqrtf(ssq) * sqrtf(__uint_as_float(g_kmax[b])) * 1.001f - 63.4786f;
  }

  // K base: j = jb + jp*32 + jf*16 + lr
  const unsigned short* kp = kf + ((size_t)b * NN + jp * 32 + lr) * MM + g * 8;
  // V base: c = wc + cf*16 + lr, col j = jb + ks*32 + g*8
  const unsigned short* pv = vbf + ((size_t)b * CC + wc + lr) * NN + g * 8;

  f32x4 acc[2][4];  // [cf][i2]
#pragma unroll
  for (int cf = 0; cf < 2; cf++)
#pragma unroll
    for (int i2 = 0; i2 < 4; i2++) acc[cf][i2] = f32x4{0.f, 0.f, 0.f, 0.f};
  float lsum = 0.f;

  char* const pbase = (char*)&P_lds[0][0][0];
  int off_s[2];  // P store byte offsets (within one buffer)
#pragma unroll
  for (int jf = 0; jf < 2; jf++) {
    const int row = if_ * 16 + lr;
    off_s[jf] = (row << 7) + (((jp * 2 + jf) * 32 + g * 8) ^ ((row & 7) << 4));
  }

  // ---- prologue: K(0); QK(0)->buf0; K(1); barrier
  f16x8 kA[2][2], kB[2][2];  // [jf][ks]
#pragma unroll
  for (int jf = 0; jf < 2; jf++)
#pragma unroll
    for (int ks = 0; ks < 2; ks++)
      kA[jf][ks] = *reinterpret_cast<const f16x8*>(kp + (size_t)(jf * 16) * MM + ks * 32);
#pragma unroll
  for (int jf = 0; jf < 2; jf++) {
    f32x4 sa = __builtin_amdgcn_mfma_f32_16x16x32_f16(kA[jf][0], qF[0],
                                                      f32x4{0.f, 0.f, 0.f, 0.f}, 0, 0, 0);
    sa = __builtin_amdgcn_mfma_f32_16x16x32_f16(kA[jf][1], qF[1], sa, 0, 0, 0);
    const float p0 = __builtin_amdgcn_exp2f(sa[0] - mhat);
    const float p1 = __builtin_amdgcn_exp2f(sa[1] - mhat);
    const float p2 = __builtin_amdgcn_exp2f(sa[2] - mhat);
    const float p3 = __builtin_amdgcn_exp2f(sa[3] - mhat);
    lsum += (p0 + p1) + (p2 + p3);
    unsigned r01, r23;
    asm volatile("v_cvt_pk_bf16_f32 %0, %1, %2" : "=v"(r01) : "v"(p0), "v"(p1));
    asm volatile("v_cvt_pk_bf16_f32 %0, %1, %2" : "=v"(r23) : "v"(p2), "v"(p3));
    *reinterpret_cast<uint2*>(pbase + off_s[jf]) = make_uint2(r01, r23);
  }
#pragma unroll
  for (int jf = 0; jf < 2; jf++)
#pragma unroll
    for (int ks = 0; ks < 2; ks++)
      kB[jf][ks] = *reinterpret_cast<const f16x8*>(kp + (size_t)(64 + jf * 16) * MM + ks * 32);
  __builtin_amdgcn_sched_barrier(0);
  asm volatile("s_waitcnt lgkmcnt(0)" ::: "memory");
  __builtin_amdgcn_s_barrier();
  __builtin_amdgcn_sched_barrier(0);

  // ---- main regions
  auto region = [&](int jb, f16x8 (&kuse)[2][2], f16x8 (&kpre)[2][2]) {
    const int par = (jb >> 6) & 1;
    const int j2 = (jb + 128) & (NN - 1);
    // V(t) load — consumed in PV below (window = QK + K-pre + exp + stores)
    bf16x8 vr[2][2];
#pragma unroll
    for (int ks = 0; ks < 2; ks++)
#pragma unroll
      for (int cf = 0; cf < 2; cf++)
        vr[ks][cf] = *reinterpret_cast<const bf16x8*>(
            pv + (size_t)cf * (16 * NN) + jb + ks * 32);
    // QK(t+1)
    f32x4 sa[2];
#pragma unroll
    for (int jf = 0; jf < 2; jf++) {
      sa[jf] = __builtin_amdgcn_mfma_f32_16x16x32_f16(kuse[jf][0], qF[0],
                                                      f32x4{0.f, 0.f, 0.f, 0.f}, 0, 0, 0);
      sa[jf] = __builtin_amdgcn_mfma_f32_16x16x32_f16(kuse[jf][1], qF[1], sa[jf], 0, 0, 0);
    }
    // K(t+2) prefetch (in flight across the barrier)
#pragma unroll
    for (int jf = 0; jf < 2; jf++)
#pragma unroll
      for (int ks = 0; ks < 2; ks++)
        kpre[jf][ks] = *reinterpret_cast<const f16x8*>(
            kp + (size_t)(j2 + jf * 16) * MM + ks * 32);
    // exp2 + pack + store P(t+1) into buf par^1
    const bool vld = (jb + 64) < NN;
    char* const pw = pbase + ((par ^ 1) << 13);
#pragma unroll
    for (int jf = 0; jf < 2; jf++) {
      const float p0 = __builtin_amdgcn_exp2f(sa[jf][0] - mhat);
      const float p1 = __builtin_amdgcn_exp2f(sa[jf][1] - mhat);
      const float p2 = __builtin_amdgcn_exp2f(sa[jf][2] - mhat);
      const float p3 = __builtin_amdgcn_exp2f(sa[jf][3] - mhat);
      if (vld) lsum += (p0 + p1) + (p2 + p3);
      unsigned r01, r23;
      asm volatile("v_cvt_pk_bf16_f32 %0, %1, %2" : "=v"(r01) : "v"(p0), "v"(p1));
      asm volatile("v_cvt_pk_bf16_f32 %0, %1, %2" : "=v"(r23) : "v"(p2), "v"(p3));
      *reinterpret_cast<uint2*>(pw + off_s[jf]) = make_uint2(r01, r23);
    }
    // PV(t) from buf par
    char* const pr = pbase + (par << 13);
    __builtin_amdgcn_s_setprio(1);
#pragma unroll
    for (int ks = 0; ks < 2; ks++) {
#pragma unroll
      for (int i2 = 0; i2 < 4; i2++) {
        const int row = i2 * 16 + lr;
        const int colb = ks * 64 + g * 16;
        const bf16x8 pf = *reinterpret_cast<const bf16x8*>(
            pr + (row << 7) + (colb ^ ((row & 7) << 4)));
        acc[0][i2] = __builtin_amdgcn_mfma_f32_16x16x32_bf16(vr[ks][0], pf, acc[0][i2], 0, 0, 0);
        acc[1][i2] = __builtin_amdgcn_mfma_f32_16x16x32_bf16(vr[ks][1], pf, acc[1][i2], 0, 0, 0);
      }
    }
    __builtin_amdgcn_s_setprio(0);
    __builtin_amdgcn_sched_barrier(0);
    asm volatile("s_waitcnt lgkmcnt(0)" ::: "memory");
    __builtin_amdgcn_s_barrier();
    __builtin_amdgcn_sched_barrier(0);
  };

  for (int tt = 0; tt < 32; tt++) {
    region(tt * 128, kB, kA);
    region(tt * 128 + 64, kA, kB);
  }

  // ---- l reduction: over g (shfl), then across the 2 j-pair waves via LDS
  lsum += __shfl_xor(lsum, 16);
  lsum += __shfl_xor(lsum, 32);
  if (l < 16) l_red[w][lr] = lsum;
  __syncthreads();
  const float gm = gamma[0];
  float inv[4];
#pragma unroll
  for (int i2 = 0; i2 < 4; i2++) inv[i2] = gm / (l_red[i2][lr] + l_red[i2 + 4][lr]);

  // ---- epilogue: out = gamma * O / l + x
#pragma unroll
  for (int cf = 0; cf < 2; cf++) {
#pragma unroll
    for (int r = 0; r < 4; r++) {
      const int c = wc + cf * 16 + g * 4 + r;
      const size_t rowo = ((size_t)b * CC + c) * NN;
#pragma unroll
      for (int i2 = 0; i2 < 4; i2++) {
        const int i = i0 + i2 * 16 + lr;
        out[rowo + i] = acc[cf][i2][r] * inv[i2] + x[rowo + i];
      }
    }
  }
}

extern "C" void kernel_launch(void* const* d_in, const int* in_sizes, int n_in,
                              void* d_out, int out_size, void* d_ws, size_t ws_size,
                              hipStream_t stream) {
  const float* x = (const float*)d_in[0];
  const float* wq = (const float*)d_in[1];
  const float* bq = (const float*)d_in[2];
  const float* wk = (const float*)d_in[3];
  const float* bk = (const float*)d_in[4];
  const float* wv = (const float*)d_in[5];
  const float* bv = (const float*)d_in[6];
  const float* gamma = (const float*)d_in[7];
  float* out = (float*)d_out;

  char* ws = (char*)d_ws;
  unsigned short* xT = (unsigned short*)(ws);                 // 32 MB [B][N][C] bf16
  unsigned short* vbf = (unsigned short*)(ws + 33554432);     // 32 MB [B][C][N] bf16
  unsigned short* qfp = (unsigned short*)(ws + 67108864);     // 4 MB  [B][N][64] fp16 (log2e-scaled)
  unsigned short* kfp = (unsigned short*)(ws + 71303168);     // 4 MB  [B][N][64] fp16
  unsigned short* wqhi = (unsigned short*)(ws + 75497472);    // 64 KB
  unsigned short* wqlo = (unsigned short*)(ws + 75563008);    // 64 KB
  unsigned short* wkhi = (unsigned short*)(ws + 75628544);    // 64 KB
  unsigned short* wklo = (unsigned short*)(ws + 75694080);    // 64 KB
  unsigned short* wvbf = (unsigned short*)(ws + 75759616);    // 512 KB

  k_wconv<<<256, 256, 0, stream>>>(wq, wk, wv, wqhi, wqlo, wkhi, wklo, wvbf);
  k_transpose<<<dim3(64, 8, 8), 256, 0, stream>>>(x, xT);
  k_proj<<<1536, 256, 0, stream>>>(xT, wqhi, wqlo, wkhi, wklo, bq, bk, wvbf, bv,
                                   qfp, kfp, vbf);
  k_attn<<<dim3(1024), 512, 0, stream>>>(qfp, kfp, vbf, x, gamma, out);
}

// Round 9
// 416.770 us; speedup vs baseline: 1.4040x; 1.4040x over previous
//
#include <hip/hip_runtime.h>
#include <hip/hip_bf16.h>

// PAM (position attention): B=8, C=512, mid=64, N=64*64=4096.
// Round 9:
//  - k_attn: 4-wave blocks (256 thr), tile 64i x 256c (c_strip=64/wave),
//    grid 1024, launch_bounds(256,2) -> 2 independent blocks/CU whose barrier
//    domains overlap (r8 lesson: never cap regs below the pipeline set; r7
//    lesson: 8-wave lockstep sums phase tails). LDS P-traffic halved vs r7
//    (c_strip 32->64). Region order {Vload, QK(t+1), Kpre(t+2), PV(t)||exp(t+1),
//    Pstore(t+1), lgkm-only barrier} — race-free buffer discipline, exp VALU
//    overlaps PV MFMA.
//  - aux unchanged from round 8 (transpose f32x4, fused proj, n-tile 256).

#define BB 8
#define CC 512
#define MM 64
#define NN 4096
#define LOG2E 1.4426950408889634f

typedef __attribute__((ext_vector_type(8))) short bf16x8;
typedef __attribute__((ext_vector_type(8))) _Float16 f16x8;
typedef __attribute__((ext_vector_type(4))) float f32x4;

__device__ unsigned g_kmax[BB];  // per-batch max ||k||^2 (uint-ordered f32)

__device__ __forceinline__ unsigned short f2bf(float f) {
  union { float f; unsigned u; } v; v.f = f;
  unsigned r = v.u + 0x7fffu + ((v.u >> 16) & 1u);  // RNE
  return (unsigned short)(r >> 16);
}
__device__ __forceinline__ float bf2f(unsigned short h) {
  union { unsigned u; float f; } v; v.u = ((unsigned)h) << 16;
  return v.f;
}
__device__ __forceinline__ unsigned short f2h(float f) {
  union { _Float16 h; unsigned short u; } v; v.h = (_Float16)f;
  return v.u;
}

// ------------- kernel 0: weight pre-conversion + g_kmax init -------------
__global__ __launch_bounds__(256) void k_wconv(
    const float* __restrict__ wq, const float* __restrict__ wk,
    const float* __restrict__ wv,
    unsigned short* __restrict__ wqhi, unsigned short* __restrict__ wqlo,
    unsigned short* __restrict__ wkhi, unsigned short* __restrict__ wklo,
    unsigned short* __restrict__ wvbf) {
  const int tid = blockIdx.x * 256 + threadIdx.x;
  if (tid < BB) g_kmax[tid] = 0u;
  if (tid < MM * CC) {
    float v = wq[tid];
    unsigned short h = f2bf(v);
    wqhi[tid] = h; wqlo[tid] = f2bf(v - bf2f(h));
    v = wk[tid]; h = f2bf(v);
    wkhi[tid] = h; wklo[tid] = f2bf(v - bf2f(h));
  }
  for (int i = tid; i < CC * CC; i += 65536) wvbf[i] = f2bf(wv[i]);
}

// ---------------- kernel 1: x [B][C][N] f32 -> xT [B][N][C] bf16 ----------------
__global__ __launch_bounds__(256) void k_transpose(const float* __restrict__ x,
                                                   unsigned short* __restrict__ xT) {
  __shared__ float tile[64][65];
  const int b = blockIdx.z, c0 = blockIdx.y * 64, n0 = blockIdx.x * 64;
  const int t = threadIdx.x;
  {
    const int nq = (t & 15) * 4, cl0 = t >> 4;
    const float* xp = x + ((size_t)b * CC + c0) * NN + n0;
#pragma unroll
    for (int r = 0; r < 4; r++) {
      const int row = cl0 + r * 16;
      const f32x4 v = *reinterpret_cast<const f32x4*>(xp + (size_t)row * NN + nq);
      tile[row][nq] = v[0]; tile[row][nq + 1] = v[1];
      tile[row][nq + 2] = v[2]; tile[row][nq + 3] = v[3];
    }
  }
  __syncthreads();
  {
    const int cq = (t & 15) * 4, nl0 = t >> 4;
    unsigned short* xtp = xT + ((size_t)b * NN + n0) * CC + c0;
#pragma unroll
    for (int r = 0; r < 4; r++) {
      const int n = nl0 + r * 16;
      const ushort4 o = make_ushort4(f2bf(tile[cq][n]), f2bf(tile[cq + 1][n]),
                                     f2bf(tile[cq + 2][n]), f2bf(tile[cq + 3][n]));
      *reinterpret_cast<ushort4*>(xtp + (size_t)n * CC + cq) = o;
    }
  }
}

// ------------- kernel 2 (fused): Q/K projection (blocks 0..511) +
//                                 V projection (blocks 512..1535, n-tile 256) -------------
__global__ __launch_bounds__(256, 2) void k_proj(
    const unsigned short* __restrict__ xT,
    const unsigned short* __restrict__ wqhi, const unsigned short* __restrict__ wqlo,
    const unsigned short* __restrict__ wkhi, const unsigned short* __restrict__ wklo,
    const float* __restrict__ bq, const float* __restrict__ bk,
    const unsigned short* __restrict__ wvbf, const float* __restrict__ bv,
    unsigned short* __restrict__ qf, unsigned short* __restrict__ kf,
    unsigned short* __restrict__ vbf) {
  __shared__ float ksl[4][4][16];
  const int t = threadIdx.x, w = t >> 6, l = t & 63, lr = l & 15, g = l >> 4;

  if (blockIdx.x < 512) {
    // ---- Q/K projection: 2-term hi/lo bf16 MFMA; q pre-scaled by log2e
    const int b = blockIdx.x & 7;
    const int n0 = (blockIdx.x >> 3) * 64;
    const unsigned short* qhp = wqhi + (size_t)(w * 16 + lr) * CC + g * 8;
    const unsigned short* qlp = wqlo + (size_t)(w * 16 + lr) * CC + g * 8;
    const unsigned short* khp = wkhi + (size_t)(w * 16 + lr) * CC + g * 8;
    const unsigned short* klp = wklo + (size_t)(w * 16 + lr) * CC + g * 8;
    const unsigned short* xp = xT + ((size_t)b * NN + n0 + lr) * CC + g * 8;
    f32x4 qacc[4], kacc[4];
#pragma unroll
    for (int nf = 0; nf < 4; nf++) {
      qacc[nf] = f32x4{0.f, 0.f, 0.f, 0.f};
      kacc[nf] = f32x4{0.f, 0.f, 0.f, 0.f};
    }
    for (int cc = 0; cc < CC; cc += 32) {
      const bf16x8 qh8 = *reinterpret_cast<const bf16x8*>(qhp + cc);
      const bf16x8 ql8 = *reinterpret_cast<const bf16x8*>(qlp + cc);
      const bf16x8 kh8 = *reinterpret_cast<const bf16x8*>(khp + cc);
      const bf16x8 kl8 = *reinterpret_cast<const bf16x8*>(klp + cc);
      bf16x8 xb[4];
#pragma unroll
      for (int nf = 0; nf < 4; nf++)
        xb[nf] = *reinterpret_cast<const bf16x8*>(xp + (size_t)nf * 16 * CC + cc);
#pragma unroll
      for (int nf = 0; nf < 4; nf++) {
        qacc[nf] = __builtin_amdgcn_mfma_f32_16x16x32_bf16(qh8, xb[nf], qacc[nf], 0, 0, 0);
        qacc[nf] = __builtin_amdgcn_mfma_f32_16x16x32_bf16(ql8, xb[nf], qacc[nf], 0, 0, 0);
        kacc[nf] = __builtin_amdgcn_mfma_f32_16x16x32_bf16(kh8, xb[nf], kacc[nf], 0, 0, 0);
        kacc[nf] = __builtin_amdgcn_mfma_f32_16x16x32_bf16(kl8, xb[nf], kacc[nf], 0, 0, 0);
      }
    }
    float bqv[4], bkv[4];
#pragma unroll
    for (int r = 0; r < 4; r++) {
      bqv[r] = bq[w * 16 + g * 4 + r];
      bkv[r] = bk[w * 16 + g * 4 + r];
    }
    float kssp[4];
#pragma unroll
    for (int nf = 0; nf < 4; nf++) {
      float ks2 = 0.f;
      unsigned short qh[4], kh[4];
#pragma unroll
      for (int r = 0; r < 4; r++) {
        const float qv = (qacc[nf][r] + bqv[r]) * LOG2E;
        const float kv = kacc[nf][r] + bkv[r];
        qh[r] = f2h(qv); kh[r] = f2h(kv);
        ks2 += kv * kv;
      }
      kssp[nf] = ks2;
      const int n = n0 + nf * 16 + lr;
      const size_t base = ((size_t)b * NN + n) * MM + w * 16 + g * 4;
      *reinterpret_cast<ushort4*>(qf + base) = make_ushort4(qh[0], qh[1], qh[2], qh[3]);
      *reinterpret_cast<ushort4*>(kf + base) = make_ushort4(kh[0], kh[1], kh[2], kh[3]);
    }
#pragma unroll
    for (int nf = 0; nf < 4; nf++) {
      kssp[nf] += __shfl_xor(kssp[nf], 16);
      kssp[nf] += __shfl_xor(kssp[nf], 32);
    }
    if (l < 16) {
#pragma unroll
      for (int nf = 0; nf < 4; nf++) ksl[w][nf][lr] = kssp[nf];
    }
    __syncthreads();
    if (t < 64) {
      const int nf2 = t >> 4, lr2 = t & 15;
      float kn2 = ksl[0][nf2][lr2] + ksl[1][nf2][lr2] + ksl[2][nf2][lr2] + ksl[3][nf2][lr2];
#pragma unroll
      for (int d = 1; d < 64; d <<= 1) kn2 = fmaxf(kn2, __shfl_xor(kn2, d));
      if (t == 0) atomicMax(&g_kmax[b], __float_as_uint(kn2));
    }
  } else {
    // ---- V projection (bf16 MFMA, pre-converted wv), n-tile 256
    const int blk = blockIdx.x - 512;                 // 0..1023
    const int b = blk >> 7, c0 = ((blk >> 4) & 7) * 64, n0 = (blk & 15) * 256;
    const int nbase = n0 + w * 64;
    f32x4 acc[4][4];
#pragma unroll
    for (int cf = 0; cf < 4; cf++)
#pragma unroll
      for (int nf = 0; nf < 4; nf++) acc[cf][nf] = f32x4{0.f, 0.f, 0.f, 0.f};
    for (int ks = 0; ks < 16; ks++) {
      const int kk = ks * 32 + g * 8;
      bf16x8 bfr[4];
#pragma unroll
      for (int nf = 0; nf < 4; nf++) {
        const int n = nbase + nf * 16 + lr;
        bfr[nf] = *reinterpret_cast<const bf16x8*>(xT + ((size_t)b * NN + n) * CC + kk);
      }
#pragma unroll
      for (int cf = 0; cf < 4; cf++) {
        const bf16x8 af = *reinterpret_cast<const bf16x8*>(
            wvbf + (size_t)(c0 + cf * 16 + lr) * CC + kk);
#pragma unroll
        for (int nf = 0; nf < 4; nf++)
          acc[cf][nf] = __builtin_amdgcn_mfma_f32_16x16x32_bf16(af, bfr[nf], acc[cf][nf], 0, 0, 0);
      }
    }
#pragma unroll
    for (int cf = 0; cf < 4; cf++) {
#pragma unroll
      for (int r = 0; r < 4; r++) {
        const int c = c0 + cf * 16 + g * 4 + r;
        const float bvv = bv[c];
#pragma unroll
        for (int nf = 0; nf < 4; nf++) {
          const int n = nbase + nf * 16 + lr;
          vbf[((size_t)b * CC + c) * NN + n] = f2bf(acc[cf][nf][r] + bvv);
        }
      }
    }
  }
}

// ---------------- kernel 3: attention + residual (bound-softmax) ----------------
// 4 waves (256 thr); block = 64 i x 256 c (ch-split 2); JT=64; grid 1024.
// launch_bounds(256,2): cap 256 regs (need ~180) -> 2 INDEPENDENT blocks/CU.
// QK fp16 swapped (A=K,B=Q): wave w owns j-frag w, computes all 4 i-frags.
// Region t: {V(t) load, QK(t+1) MFMA, K(t+2) prefetch, PV(t) || exp2(t+1),
//            P-store(t+1)->buf^1, lgkm-only barrier}. Buffer discipline is
//            race-free: stores target buf^1, reads target buf, barrier between
//            a buffer's stores and its reads.
__global__ __launch_bounds__(256, 2) void k_attn(
    const unsigned short* __restrict__ qf, const unsigned short* __restrict__ kf,
    const unsigned short* __restrict__ vbf, const float* __restrict__ x,
    const float* __restrict__ gamma, float* __restrict__ out) {
  __shared__ unsigned short P_lds[2][64][64];  // 8 KB/buf, XOR-swizzled
  __shared__ float l_red[4][4][16];
  const int b = blockIdx.x & 7;      // batch-pinned XCD swizzle
  const int idx = blockIdx.x >> 3;   // 0..127
  const int i0 = (idx >> 1) * 64;
  const int ch = idx & 1;
  const int t = threadIdx.x, w = t >> 6, l = t & 63, lr = l & 15, g = l >> 4;
  const int jf = w;                  // j-frag owner
  const int wc = ch * 256 + w * 64;  // PV channel strip (64 c per wave)

  // ---- Q fragments (fp16, pre-scaled by log2e): 4 i-frags
  f16x8 qF[4][2];
#pragma unroll
  for (int q = 0; q < 4; q++) {
    const int i = i0 + q * 16 + lr;
#pragma unroll
    for (int ks = 0; ks < 2; ks++)
      qF[q][ks] = *reinterpret_cast<const f16x8*>(qf + ((size_t)b * NN + i) * MM + ks * 32 + g * 8);
  }
  // ---- mhat[q] (log2 units): ||q~|| * max||k|| * (1+eps) - 44*log2e
  float mhat[4];
  {
    const float kroot = sqrtf(__uint_as_float(g_kmax[b])) * 1.001f;
#pragma unroll
    for (int q = 0; q < 4; q++) {
      float ssq = 0.f;
#pragma unroll
      for (int ks = 0; ks < 2; ks++)
#pragma unroll
        for (int e = 0; e < 8; e++) {
          const float qv = (float)qF[q][ks][e];
          ssq += qv * qv;
        }
      ssq += __shfl_xor(ssq, 16);
      ssq += __shfl_xor(ssq, 32);
      mhat[q] = sqrtf(ssq) * kroot - 63.4786f;
    }
  }

  // K base: j = jb + jf*16 + lr
  const unsigned short* kp = kf + ((size_t)b * NN + jf * 16 + lr) * MM + g * 8;
  // V base: c = wc + cf*16 + lr, col j = jb + ks*32 + g*8
  const unsigned short* pv = vbf + ((size_t)b * CC + wc + lr) * NN + g * 8;

  f32x4 acc[4][4];  // [cf][i2]
#pragma unroll
  for (int cf = 0; cf < 4; cf++)
#pragma unroll
    for (int i2 = 0; i2 < 4; i2++) acc[cf][i2] = f32x4{0.f, 0.f, 0.f, 0.f};
  float lsum[4] = {0.f, 0.f, 0.f, 0.f};

  char* const pbase = (char*)&P_lds[0][0][0];
  const int rswz = (lr & 7) << 4;   // read-side XOR (row&7 == lr&7 for all i2)
  int off_s[4];                      // store byte offsets within one buffer
#pragma unroll
  for (int q = 0; q < 4; q++) {
    const int row = q * 16 + lr;
    off_s[q] = (row << 7) + ((jf * 32 + g * 8) ^ ((row & 7) << 4));
  }

  // ---- prologue: K(0); QK(0)->buf0; K(1); barrier
  f16x8 kA[2], kB[2];
#pragma unroll
  for (int ks = 0; ks < 2; ks++)
    kA[ks] = *reinterpret_cast<const f16x8*>(kp + (size_t)ks * 32);
#pragma unroll
  for (int q = 0; q < 4; q++) {
    f32x4 sa = __builtin_amdgcn_mfma_f32_16x16x32_f16(kA[0], qF[q][0],
                                                      f32x4{0.f, 0.f, 0.f, 0.f}, 0, 0, 0);
    sa = __builtin_amdgcn_mfma_f32_16x16x32_f16(kA[1], qF[q][1], sa, 0, 0, 0);
    const float p0 = __builtin_amdgcn_exp2f(sa[0] - mhat[q]);
    const float p1 = __builtin_amdgcn_exp2f(sa[1] - mhat[q]);
    const float p2 = __builtin_amdgcn_exp2f(sa[2] - mhat[q]);
    const float p3 = __builtin_amdgcn_exp2f(sa[3] - mhat[q]);
    lsum[q] += (p0 + p1) + (p2 + p3);
    unsigned r01, r23;
    asm volatile("v_cvt_pk_bf16_f32 %0, %1, %2" : "=v"(r01) : "v"(p0), "v"(p1));
    asm volatile("v_cvt_pk_bf16_f32 %0, %1, %2" : "=v"(r23) : "v"(p2), "v"(p3));
    *reinterpret_cast<uint2*>(pbase + off_s[q]) = make_uint2(r01, r23);
  }
#pragma unroll
  for (int ks = 0; ks < 2; ks++)
    kB[ks] = *reinterpret_cast<const f16x8*>(kp + (size_t)64 * MM + ks * 32);
  __builtin_amdgcn_sched_barrier(0);
  asm volatile("s_waitcnt lgkmcnt(0)" ::: "memory");
  __builtin_amdgcn_s_barrier();
  __builtin_amdgcn_sched_barrier(0);

  // ---- main regions
  auto region = [&](int jb, f16x8 (&kuse)[2], f16x8 (&kpre)[2]) {
    const int par = (jb >> 6) & 1;
    const int j2 = (jb + 128) & (NN - 1);
    // V(t): consumed in PV below (window = QK + Kpre + exp issue)
    bf16x8 vr[2][4];
#pragma unroll
    for (int ks = 0; ks < 2; ks++)
#pragma unroll
      for (int cf = 0; cf < 4; cf++)
        vr[ks][cf] = *reinterpret_cast<const bf16x8*>(
            pv + (size_t)cf * (16 * NN) + jb + ks * 32);
    // QK(t+1)
    f32x4 sa[4];
#pragma unroll
    for (int q = 0; q < 4; q++) {
      sa[q] = __builtin_amdgcn_mfma_f32_16x16x32_f16(kuse[0], qF[q][0],
                                                     f32x4{0.f, 0.f, 0.f, 0.f}, 0, 0, 0);
      sa[q] = __builtin_amdgcn_mfma_f32_16x16x32_f16(kuse[1], qF[q][1], sa[q], 0, 0, 0);
    }
    // K(t+2) prefetch (stays in flight across the barrier)
#pragma unroll
    for (int ks = 0; ks < 2; ks++)
      kpre[ks] = *reinterpret_cast<const f16x8*>(kp + (size_t)j2 * MM + ks * 32);
    // PV(t) from buf par  (exp2/pack of t+1 below co-issues on VALU pipe)
    char* const pr = pbase + (par << 13);
    __builtin_amdgcn_s_setprio(1);
#pragma unroll
    for (int ks = 0; ks < 2; ks++) {
#pragma unroll
      for (int i2 = 0; i2 < 4; i2++) {
        const int row = i2 * 16 + lr;
        const bf16x8 pf = *reinterpret_cast<const bf16x8*>(
            pr + (row << 7) + ((ks * 64 + g * 16) ^ rswz));
#pragma unroll
        for (int cf = 0; cf < 4; cf++)
          acc[cf][i2] = __builtin_amdgcn_mfma_f32_16x16x32_bf16(vr[ks][cf], pf, acc[cf][i2], 0, 0, 0);
      }
    }
    __builtin_amdgcn_s_setprio(0);
    // exp2 + pack + store P(t+1) into buf par^1
    const bool vld = (jb + 64) < NN;
    char* const pw = pbase + ((par ^ 1) << 13);
#pragma unroll
    for (int q = 0; q < 4; q++) {
      const float p0 = __builtin_amdgcn_exp2f(sa[q][0] - mhat[q]);
      const float p1 = __builtin_amdgcn_exp2f(sa[q][1] - mhat[q]);
      const float p2 = __builtin_amdgcn_exp2f(sa[q][2] - mhat[q]);
      const float p3 = __builtin_amdgcn_exp2f(sa[q][3] - mhat[q]);
      if (vld) lsum[q] += (p0 + p1) + (p2 + p3);
      unsigned r01, r23;
      asm volatile("v_cvt_pk_bf16_f32 %0, %1, %2" : "=v"(r01) : "v"(p0), "v"(p1));
      asm volatile("v_cvt_pk_bf16_f32 %0, %1, %2" : "=v"(r23) : "v"(p2), "v"(p3));
      *reinterpret_cast<uint2*>(pw + off_s[q]) = make_uint2(r01, r23);
    }
    // barrier: drain LDS only; global prefetches (K) stay in flight
    __builtin_amdgcn_sched_barrier(0);
    asm volatile("s_waitcnt lgkmcnt(0)" ::: "memory");
    __builtin_amdgcn_s_barrier();
    __builtin_amdgcn_sched_barrier(0);
  };

  for (int tt = 0; tt < 32; tt++) {
    region(tt * 128, kB, kA);
    region(tt * 128 + 64, kA, kB);
  }

  // ---- l reduction: over g (shfl), then across the 4 j-frag waves via LDS
#pragma unroll
  for (int q = 0; q < 4; q++) {
    lsum[q] += __shfl_xor(lsum[q], 16);
    lsum[q] += __shfl_xor(lsum[q], 32);
  }
  if (l < 16) {
#pragma unroll
    for (int q = 0; q < 4; q++) l_red[w][q][lr] = lsum[q];
  }
  __syncthreads();
  const float gm = gamma[0];
  float inv[4];
#pragma unroll
  for (int i2 = 0; i2 < 4; i2++)
    inv[i2] = gm / (l_red[0][i2][lr] + l_red[1][i2][lr] +
                    l_red[2][i2][lr] + l_red[3][i2][lr]);

  // ---- epilogue: out = gamma * O / l + x
#pragma unroll
  for (int cf = 0; cf < 4; cf++) {
#pragma unroll
    for (int r = 0; r < 4; r++) {
      const int c = wc + cf * 16 + g * 4 + r;
      const size_t rowo = ((size_t)b * CC + c) * NN;
#pragma unroll
      for (int i2 = 0; i2 < 4; i2++) {
        const int i = i0 + i2 * 16 + lr;
        out[rowo + i] = acc[cf][i2][r] * inv[i2] + x[rowo + i];
      }
    }
  }
}

extern "C" void kernel_launch(void* const* d_in, const int* in_sizes, int n_in,
                              void* d_out, int out_size, void* d_ws, size_t ws_size,
                              hipStream_t stream) {
  const float* x = (const float*)d_in[0];
  const float* wq = (const float*)d_in[1];
  const float* bq = (const float*)d_in[2];
  const float* wk = (const float*)d_in[3];
  const float* bk = (const float*)d_in[4];
  const float* wv = (const float*)d_in[5];
  const float* bv = (const float*)d_in[6];
  const float* gamma = (const float*)d_in[7];
  float* out = (float*)d_out;

  char* ws = (char*)d_ws;
  unsigned short* xT = (unsigned short*)(ws);                 // 32 MB [B][N][C] bf16
  unsigned short* vbf = (unsigned short*)(ws + 33554432);     // 32 MB [B][C][N] bf16
  unsigned short* qfp = (unsigned short*)(ws + 67108864);     // 4 MB  [B][N][64] fp16 (log2e-scaled)
  unsigned short* kfp = (unsigned short*)(ws + 71303168);     // 4 MB  [B][N][64] fp16
  unsigned short* wqhi = (unsigned short*)(ws + 75497472);    // 64 KB
  unsigned short* wqlo = (unsigned short*)(ws + 75563008);    // 64 KB
  unsigned short* wkhi = (unsigned short*)(ws + 75628544);    // 64 KB
  unsigned short* wklo = (unsigned short*)(ws + 75694080);    // 64 KB
  unsigned short* wvbf = (unsigned short*)(ws + 75759616);    // 512 KB

  k_wconv<<<256, 256, 0, stream>>>(wq, wk, wv, wqhi, wqlo, wkhi, wklo, wvbf);
  k_transpose<<<dim3(64, 8, 8), 256, 0, stream>>>(x, xT);
  k_proj<<<1536, 256, 0, stream>>>(xT, wqhi, wqlo, wkhi, wklo, bq, bk, wvbf, bv,
                                   qfp, kfp, vbf);
  k_attn<<<dim3(1024), 256, 0, stream>>>(qfp, kfp, vbf, x, gamma, out);
}